// Round 16
// baseline (211.237 us; speedup 1.0000x reference)
//
#include <hip/hip_runtime.h>

// 2-layer LSTM (B=4096, T=256, I=38, H1=50, H2=15) + FC on last step.
// R16: SB=16, 256 thr = 4 waves (1 wave/SIMD), grid=256 (1 block/CU).
// Swapped-operand MFMA: wave wv owns tiles {wv,wv+4,wv+8,wv+12} (+tile16 on
// wv3) -> 4 dense in-register LSTM updates per lane (unit 4*tile+lk, seq lm).
// DS A-reads halved vs 8-wave config; 4-wave barrier; slot-wise MFMA/update
// interleave gives ILP within one wave. One barrier/step; float2 x staging
// with 2-step-ahead prefetch; L2 pipelined one step behind L1.

typedef _Float16 f16x8 __attribute__((ext_vector_type(8)));
typedef _Float16 f16x2 __attribute__((ext_vector_type(2)));
typedef float    f32x4 __attribute__((ext_vector_type(4)));

#if __has_builtin(__builtin_amdgcn_exp2f)
#define DEV_EXP2(x) __builtin_amdgcn_exp2f(x)
#else
#define DEV_EXP2(x) exp2f(x)
#endif
#if __has_builtin(__builtin_amdgcn_rcpf)
#define DEV_RCP(x) __builtin_amdgcn_rcpf(x)
#else
#define DEV_RCP(x) (1.0f/(x))
#endif

#define I1 38
#define H1 50
#define H2 15
#define NC 14
#define TT 256
#define SB 16
// A-row (f16): [x:0..37 | h1:38..87 | h2:88..102 | zero:..127 | pad..135]
#define XS 136
#define NTH 256
#define L2E 2.885390081777927f
#define L1E 1.442695040888963f

#define MF(A,B,C) __builtin_amdgcn_mfma_f32_16x16x32_f16((A),(B),(C),0,0,0)

__device__ __forceinline__ float sigm(float v)  { return DEV_RCP(1.f + DEV_EXP2(-L1E * v)); }
__device__ __forceinline__ float tanh_f(float v){ return 1.f - 2.f * DEV_RCP(1.f + DEV_EXP2(L2E * v)); }

__launch_bounds__(NTH, 1)
__global__ void lstm2_fused(const float* __restrict__ x,
                            const float* __restrict__ w_ih1, const float* __restrict__ w_hh1,
                            const float* __restrict__ b_ih1, const float* __restrict__ b_hh1,
                            const float* __restrict__ w_ih2, const float* __restrict__ w_hh2,
                            const float* __restrict__ b_ih2, const float* __restrict__ b_hh2,
                            const float* __restrict__ w_fc, const float* __restrict__ b_fc,
                            float* __restrict__ out)
{
  __shared__ __align__(16) _Float16 bufA[2][SB][XS];

  const int tid  = threadIdx.x;
  const int wv   = tid >> 6;          // 0..3
  const int lane = tid & 63;
  const int lm   = lane & 15;         // seq (D col); W-fragment row
  const int lk   = lane >> 4;         // k chunk; D row group = local unit
  const int blk  = blockIdx.x;
  const float* xblk = x + (size_t)blk * SB * TT * I1;

  // ---- zero A buffers ----
  for (int i = tid; i < 2*SB*XS; i += NTH) ((_Float16*)bufA)[i] = (_Float16)0.f;

  // ---- weight element fetch (unified-k, gate-row r = 4u+g) ----
  auto welem = [&](bool il1, bool valid, int u, int g, int k) -> _Float16 {
    float w = 0.f;
    if (valid) {
      if (il1) {
        if (k < I1)                w = w_ih1[(g*H1 + u)*I1 + k];
        else if (k < I1 + H1)      w = w_hh1[(g*H1 + u)*H1 + (k - I1)];
      } else {
        if (k >= I1 && k < I1+H1)             w = w_ih2[(g*H2 + u)*H1 + (k - I1)];
        else if (k >= I1+H1 && k < I1+H1+H2)  w = w_hh2[(g*H2 + u)*H2 + (k - I1 - H1)];
      }
    }
    return (_Float16)w;
  };

  // fragment row for tile ts: gate-row r = ts*16+lm -> unit quad r>>2, gate r&3
  auto wfrag = [&](int ts, int ks) -> f16x8 {
    const int r = ts*16 + lm, q = r >> 2, g = r & 3;
    const bool il1 = (q < H1);
    const int u = il1 ? q : (q - H1);
    f16x8 v;
    #pragma unroll
    for (int e = 0; e < 8; ++e) v[e] = welem(il1, true, u, g, ks*32 + lk*8 + e);
    return v;
  };

  f16x8 W0[3], W1[3], W2[3], W3[4], W16[3];
  #pragma unroll
  for (int ks = 0; ks < 3; ++ks) {
    W0[ks] = wfrag(wv,      ks);
    W1[ks] = wfrag(wv + 4,  ks);
    W2[ks] = wfrag(wv + 8,  ks);
    W3[ks] = wfrag(wv + 12, ks);
  }
  W3[3] = wfrag(wv + 12, 3);
  #pragma unroll
  for (int j = 0; j < 3; ++j) {       // tile16: rows lm<4 = unit 64 (L2 u14), g=lm
    f16x8 v;
    #pragma unroll
    for (int e = 0; e < 8; ++e) v[e] = welem(false, lm < 4, 14, lm & 3, (j+1)*32 + lk*8 + e);
    W16[j] = v;
  }

  // ---- biases (C-init): slot s -> unit 4*(ts)+lk, gate m ----
  auto bval = [&](int ts, int m) -> float {
    const int u = 4*ts + lk;
    if (u < H1) return b_ih1[m*H1 + u] + b_hh1[m*H1 + u];
    const int ur = u - H1;
    return b_ih2[m*H2 + ur] + b_hh2[m*H2 + ur];
  };
  float sb0[4], sb1[4], sb2[4], sb3[4], sbC[4];
  #pragma unroll
  for (int m = 0; m < 4; ++m) {
    sb0[m] = bval(wv, m);
    sb1[m] = bval(wv + 4, m);
    sb2[m] = bval(wv + 8, m);
    sb3[m] = bval(wv + 12, m);
    sbC[m] = b_ih2[m*H2 + 14] + b_hh2[m*H2 + 14];
  }

  // ---- update dest columns ----
  const int d0 = 38 + (4*wv + lk);              // slots 0-2: always L1
  const int d1 = 38 + (4*(wv+4) + lk);
  const int d2 = 38 + (4*(wv+8) + lk);
  const int u3 = 4*(wv+12) + lk;                // 48..63
  const bool il13 = (u3 < H1);
  const int d3 = il13 ? (38 + u3) : (88 + (u3 - H1));
  const bool w16 = (wv == 3);

  // ---- x staging: 304 float2/step over 256 threads ----
  const int c1x = tid + 256;
  const bool v1 = (c1x < SB*19);                // tid < 48
  const int s0 = tid / 19,  q0 = tid % 19;
  const int s1x = c1x / 19, q1x = c1x % 19;
  const int gb0 = s0*TT*I1 + 2*q0;
  const int gb1 = v1 ? (s1x*TT*I1 + 2*q1x) : 0;
  const int lb0 = s0*XS + 2*q0;
  const int lb1 = v1 ? (s1x*XS + 2*q1x) : 0;

  auto st2 = [&](_Float16* dst, float2 v) {
    f16x2 h; h[0] = (_Float16)v.x; h[1] = (_Float16)v.y;
    *(f16x2*)dst = h;
  };

  __syncthreads();              // zeros visible
  {                             // stage x(0)
    _Float16* b0 = &bufA[0][0][0];
    st2(b0 + lb0, *(const float2*)(xblk + gb0));
    if (v1) st2(b0 + lb1, *(const float2*)(xblk + gb1));
  }
  float2 xA0v = {0.f, 0.f}, xA1v = {0.f, 0.f};
  float2 xB0v = {0.f, 0.f}, xB1v = {0.f, 0.f};
  xA0v = *(const float2*)(xblk + gb0 + I1);     // prefetch x(1)
  if (v1) xA1v = *(const float2*)(xblk + gb1 + I1);
  __syncthreads();

  float c0s = 0.f, c1s = 0.f, c2s = 0.f, c3s = 0.f, cC = 0.f;

#define UPD_L1(ACC, CVAR, DCOL, T) do {                                         \
    if ((T) < TT) {                                                             \
      float ig = sigm((ACC)[0]), fg = sigm((ACC)[1]);                           \
      float gg = tanh_f((ACC)[2]), og = sigm((ACC)[3]);                         \
      CVAR = fg*CVAR + ig*gg;                                                   \
      nxt[lm*XS + (DCOL)] = (_Float16)(og * tanh_f(CVAR));                      \
    }                                                                           \
  } while (0)

#define STEP(T, XC0, XC1, XN0, XN1) do {                                        \
    _Float16* cur = &bufA[(T) & 1][0][0];                                       \
    _Float16* nxt = &bufA[((T) & 1) ^ 1][0][0];                                 \
    if ((T) + 2 < TT) {                                                         \
      const int go = ((T) + 2) * I1;                                            \
      XN0 = *(const float2*)(xblk + gb0 + go);                                  \
      if (v1) XN1 = *(const float2*)(xblk + gb1 + go);                          \
    }                                                                           \
    f16x8 a0 = *(const f16x8*)(cur + lm*XS +      lk*8);                        \
    f16x8 a1 = *(const f16x8*)(cur + lm*XS + 32 + lk*8);                        \
    f16x8 a2 = *(const f16x8*)(cur + lm*XS + 64 + lk*8);                        \
    f16x8 a3 = *(const f16x8*)(cur + lm*XS + 96 + lk*8);                        \
    {                                                                           \
      f32x4 acc = (f32x4){sb0[0], sb0[1], sb0[2], sb0[3]};                      \
      acc = MF(W0[0], a0, acc); acc = MF(W0[1], a1, acc);                       \
      acc = MF(W0[2], a2, acc);                                                 \
      UPD_L1(acc, c0s, d0, T);                                                  \
    }                                                                           \
    {                                                                           \
      f32x4 acc = (f32x4){sb1[0], sb1[1], sb1[2], sb1[3]};                      \
      acc = MF(W1[0], a0, acc); acc = MF(W1[1], a1, acc);                       \
      acc = MF(W1[2], a2, acc);                                                 \
      UPD_L1(acc, c1s, d1, T);                                                  \
    }                                                                           \
    {                                                                           \
      f32x4 acc = (f32x4){sb2[0], sb2[1], sb2[2], sb2[3]};                      \
      acc = MF(W2[0], a0, acc); acc = MF(W2[1], a1, acc);                       \
      acc = MF(W2[2], a2, acc);                                                 \
      UPD_L1(acc, c2s, d2, T);                                                  \
    }                                                                           \
    {                                                                           \
      f32x4 acc = (f32x4){sb3[0], sb3[1], sb3[2], sb3[3]};                      \
      acc = MF(W3[0], a0, acc); acc = MF(W3[1], a1, acc);                       \
      acc = MF(W3[2], a2, acc); acc = MF(W3[3], a3, acc);                       \
      const bool up = il13 ? ((T) < TT) : ((T) >= 1);                           \
      if (up) {                                                                 \
        float ig = sigm(acc[0]), fg = sigm(acc[1]);                             \
        float gg = tanh_f(acc[2]), og = sigm(acc[3]);                           \
        c3s = fg*c3s + ig*gg;                                                   \
        nxt[lm*XS + d3] = (_Float16)(og * tanh_f(c3s));                         \
      }                                                                         \
    }                                                                           \
    if (w16) {                                                                  \
      f32x4 acc = (f32x4){sbC[0], sbC[1], sbC[2], sbC[3]};                      \
      acc = MF(W16[0], a1, acc); acc = MF(W16[1], a2, acc);                     \
      acc = MF(W16[2], a3, acc);                                                \
      if (lk == 0 && (T) >= 1) {                                                \
        float ig = sigm(acc[0]), fg = sigm(acc[1]);                             \
        float gg = tanh_f(acc[2]), og = sigm(acc[3]);                           \
        cC = fg*cC + ig*gg;                                                     \
        nxt[lm*XS + 102] = (_Float16)(og * tanh_f(cC));                         \
      }                                                                         \
    }                                                                           \
    if ((T) + 1 < TT) {                                                         \
      st2(nxt + lb0, XC0);                                                      \
      if (v1) st2(nxt + lb1, XC1);                                              \
    }                                                                           \
    __syncthreads();                                                            \
  } while (0)

  int t = 0;
  for (;;) {
    STEP(t, xA0v, xA1v, xB0v, xB1v);
    if (++t > TT) break;
    STEP(t, xB0v, xB1v, xA0v, xA1v);
    if (++t > TT) break;
  }
#undef STEP
#undef UPD_L1

  // ---- FC on h2(255) (bufA[1], cols 88..102) ----
  if (tid < SB*NC) {
    int s = tid / NC, n = tid % NC;
    float acc = b_fc[n];
    #pragma unroll
    for (int u = 0; u < H2; ++u)
      acc += (float)bufA[1][s][88 + u] * w_fc[n*H2 + u];
    out[((size_t)blk*SB + s)*NC + n] = acc;
  }
}

extern "C" void kernel_launch(void* const* d_in, const int* in_sizes, int n_in,
                              void* d_out, int out_size, void* d_ws, size_t ws_size,
                              hipStream_t stream) {
  (void)n_in; (void)d_ws; (void)ws_size; (void)out_size;
  const float* x     = (const float*)d_in[0];
  const float* w_ih1 = (const float*)d_in[1];
  const float* w_hh1 = (const float*)d_in[2];
  const float* b_ih1 = (const float*)d_in[3];
  const float* b_hh1 = (const float*)d_in[4];
  const float* w_ih2 = (const float*)d_in[5];
  const float* w_hh2 = (const float*)d_in[6];
  const float* b_ih2 = (const float*)d_in[7];
  const float* b_hh2 = (const float*)d_in[8];
  const float* w_fc  = (const float*)d_in[9];
  const float* b_fc  = (const float*)d_in[10];
  float* out = (float*)d_out;

  const int B = in_sizes[0] / (TT * I1);   // 4096
  dim3 grid(B / SB), block(NTH);
  lstm2_fused<<<grid, block, 0, stream>>>(x, w_ih1, w_hh1, b_ih1, b_hh1,
                                          w_ih2, w_hh2, b_ih2, b_hh2,
                                          w_fc, b_fc, out);
}

// Round 17
// 167.128 us; speedup vs baseline: 1.2639x; 1.2639x over previous
//
#include <hip/hip_runtime.h>

// 2-layer LSTM (B=4096, T=256, I=38, H1=50, H2=15) + FC on last step.
// R17 = R10 (swapped-operand MFMA, in-register update, SB=16, 512 thr/8
// waves, 1 block/CU, one barrier/step) + surgical trims:
//  - wave-uniform k-mask: slot1 runs ks0-2 (wv<4), ks0-3 (wv4), ks1-3 (wv>4);
//    a3 read only where used (wv0 tile16, wv>=4). No zero-weight MFMAs.
//  - float2 x loads + f16x2 LDS writes (one chunk per thread, tid<304).
//  - raw "s_waitcnt lgkmcnt(0); s_barrier" per step (no vmcnt drain).

typedef _Float16 f16x8 __attribute__((ext_vector_type(8)));
typedef _Float16 f16x2 __attribute__((ext_vector_type(2)));
typedef float    f32x4 __attribute__((ext_vector_type(4)));

#if __has_builtin(__builtin_amdgcn_exp2f)
#define DEV_EXP2(x) __builtin_amdgcn_exp2f(x)
#else
#define DEV_EXP2(x) exp2f(x)
#endif
#if __has_builtin(__builtin_amdgcn_rcpf)
#define DEV_RCP(x) __builtin_amdgcn_rcpf(x)
#else
#define DEV_RCP(x) (1.0f/(x))
#endif

#define I1 38
#define H1 50
#define H2 15
#define NC 14
#define TT 256
#define SB 16
// A-row (f16): [x:0..37 | h1:38..87 | h2:88..102 | zero:..127 | pad..135]
#define XS 136
#define NTH 512
#define L2E 2.885390081777927f
#define L1E 1.442695040888963f

#define MF(A,B,C) __builtin_amdgcn_mfma_f32_16x16x32_f16((A),(B),(C),0,0,0)
#define BARRIER() asm volatile("s_waitcnt lgkmcnt(0)\n\ts_barrier" ::: "memory")

__device__ __forceinline__ float sigm(float v)  { return DEV_RCP(1.f + DEV_EXP2(-L1E * v)); }
__device__ __forceinline__ float tanh_f(float v){ return 1.f - 2.f * DEV_RCP(1.f + DEV_EXP2(L2E * v)); }

__launch_bounds__(NTH, 1)
__global__ void lstm2_fused(const float* __restrict__ x,
                            const float* __restrict__ w_ih1, const float* __restrict__ w_hh1,
                            const float* __restrict__ b_ih1, const float* __restrict__ b_hh1,
                            const float* __restrict__ w_ih2, const float* __restrict__ w_hh2,
                            const float* __restrict__ b_ih2, const float* __restrict__ b_hh2,
                            const float* __restrict__ w_fc, const float* __restrict__ b_fc,
                            float* __restrict__ out)
{
  __shared__ __align__(16) _Float16 bufA[2][SB][XS];

  const int tid  = threadIdx.x;
  const int wv   = tid >> 6;          // 0..7
  const int lane = tid & 63;
  const int lm   = lane & 15;         // seq (D col); W-fragment row
  const int lk   = lane >> 4;         // k chunk; D row group = local unit
  const int blk  = blockIdx.x;
  const float* xblk = x + (size_t)blk * SB * TT * I1;

  // ---- zero A buffers ----
  for (int i = tid; i < 2*SB*XS; i += NTH) ((_Float16*)bufA)[i] = (_Float16)0.f;

  // ---- weight element fetch (unified-k, gate-row r = 4u+g) ----
  auto welem = [&](bool il1, bool valid, int u, int g, int k) -> _Float16 {
    float w = 0.f;
    if (valid) {
      if (il1) {
        if (k < I1)                w = w_ih1[(g*H1 + u)*I1 + k];
        else if (k < I1 + H1)      w = w_hh1[(g*H1 + u)*H1 + (k - I1)];
      } else {
        if (k >= I1 && k < I1+H1)             w = w_ih2[(g*H2 + u)*H1 + (k - I1)];
        else if (k >= I1+H1 && k < I1+H1+H2)  w = w_hh2[(g*H2 + u)*H2 + (k - I1 - H1)];
      }
    }
    return (_Float16)w;
  };

  // ---- W fragments: row = lm (gate-row within tile), k = ks*32 + lk*8 + e ----
  const int t1 = wv + 8;
  const int r0 = wv*16 + lm, u0f = r0 >> 2, g0 = r0 & 3;     // tile wv: always L1
  const int r1 = t1*16 + lm, q1 = r1 >> 2, g1 = r1 & 3;
  const bool il1f = (q1 < H1);
  const int  u1f = il1f ? q1 : (q1 - H1);
  const bool w16 = (wv == 0);
  const bool c16 = w16 && (lm < 4);          // tile16 valid rows: unit 64, g=lm

  // wave-uniform k-mask for slot1: wv<4 -> ks0-2; wv==4 -> ks0-3; wv>4 -> ks1-3
  const bool s1k0 = (wv <= 4);
  const bool s1k3 = (wv >= 4);
  const bool needA3 = w16 || s1k3;

  f16x8 W0[3], W1[4], W16[3];
  #pragma unroll
  for (int ks = 0; ks < 3; ++ks) {
    f16x8 v;
    #pragma unroll
    for (int e = 0; e < 8; ++e) v[e] = welem(true, true, u0f, g0, ks*32 + lk*8 + e);
    W0[ks] = v;
  }
  #pragma unroll
  for (int ks = 0; ks < 4; ++ks) {
    f16x8 v;
    #pragma unroll
    for (int e = 0; e < 8; ++e) v[e] = welem(il1f, true, u1f, g1, ks*32 + lk*8 + e);
    W1[ks] = v;
  }
  #pragma unroll
  for (int j = 0; j < 3; ++j) {
    f16x8 v;
    #pragma unroll
    for (int e = 0; e < 8; ++e) v[e] = welem(false, c16, 14, lm & 3, (j+1)*32 + lk*8 + e);
    W16[j] = v;
  }

  // ---- update geometry: lane (lm, lk) owns (unit 4*tile+lk, seq lm) ----
  const int uS0 = 4*wv + lk;                 // slot0: 0..31, always L1
  const int d0  = 38 + uS0;
  const int uS1 = 32 + 4*wv + lk;            // slot1: 32..63
  const bool il1u = (uS1 < H1);
  const int  uS1r = il1u ? uS1 : (uS1 - H1);
  const int  d1   = il1u ? (38 + uS1) : (88 + uS1r);
  const bool hasC = w16 && (lk == 0);        // tile16: unit 64 = L2 u14

  // ---- biases into MFMA C-init ----
  float sb0[4], sb1[4], sbC[4];
  #pragma unroll
  for (int m = 0; m < 4; ++m) {
    sb0[m] = b_ih1[m*H1 + uS0] + b_hh1[m*H1 + uS0];
    sb1[m] = il1u ? (b_ih1[m*H1 + uS1] + b_hh1[m*H1 + uS1])
                  : (b_ih2[m*H2 + uS1r] + b_hh2[m*H2 + uS1r]);
    sbC[m] = b_ih2[m*H2 + 14] + b_hh2[m*H2 + 14];
  }

  // ---- x staging: 304 float2 chunks, one per thread (tid < 304) ----
  const bool vx = (tid < SB*19);             // 19 float2 per seq-step
  const int s0 = vx ? (tid / 19) : 0, q0 = vx ? (tid % 19) : 0;
  const int gb0 = s0*TT*I1 + 2*q0;
  const int lb0 = s0*XS + 2*q0;

  auto st2 = [&](_Float16* dst, float2 v) {
    f16x2 h; h[0] = (_Float16)v.x; h[1] = (_Float16)v.y;
    *(f16x2*)dst = h;
  };

  __syncthreads();              // zeros visible
  if (vx) st2(&bufA[0][0][0] + lb0, *(const float2*)(xblk + gb0));   // x(0)
  float2 xA0 = {0.f, 0.f}, xB0 = {0.f, 0.f};
  if (vx) xA0 = *(const float2*)(xblk + gb0 + I1);                   // prefetch x(1)
  __syncthreads();

  float cS0 = 0.f, cS1 = 0.f, cC = 0.f;

#define STEP(T, XC0, XN0) do {                                                  \
    _Float16* cur = &bufA[(T) & 1][0][0];                                       \
    _Float16* nxt = &bufA[((T) & 1) ^ 1][0][0];                                 \
    if (vx && (T) + 2 < TT)                                                     \
      XN0 = *(const float2*)(xblk + gb0 + ((T) + 2) * I1);                      \
    f16x8 a0 = *(const f16x8*)(cur + lm*XS +      lk*8);                        \
    f16x8 a1 = *(const f16x8*)(cur + lm*XS + 32 + lk*8);                        \
    f16x8 a2 = *(const f16x8*)(cur + lm*XS + 64 + lk*8);                        \
    f16x8 a3 = (f16x8)(_Float16)0.f;                                            \
    if (needA3) a3 = *(const f16x8*)(cur + lm*XS + 96 + lk*8);                  \
    {                                                                           \
      f32x4 acc = (f32x4){sb0[0], sb0[1], sb0[2], sb0[3]};                      \
      acc = MF(W0[0], a0, acc);                                                 \
      acc = MF(W0[1], a1, acc);                                                 \
      acc = MF(W0[2], a2, acc);                                                 \
      if ((T) < TT) {                                                           \
        float ig = sigm(acc[0]), fg = sigm(acc[1]);                             \
        float gg = tanh_f(acc[2]), og = sigm(acc[3]);                           \
        cS0 = fg*cS0 + ig*gg;                                                   \
        nxt[lm*XS + d0] = (_Float16)(og * tanh_f(cS0));                         \
      }                                                                         \
    }                                                                           \
    {                                                                           \
      f32x4 acc = (f32x4){sb1[0], sb1[1], sb1[2], sb1[3]};                      \
      if (s1k0) acc = MF(W1[0], a0, acc);                                       \
      acc = MF(W1[1], a1, acc);                                                 \
      acc = MF(W1[2], a2, acc);                                                 \
      if (s1k3) acc = MF(W1[3], a3, acc);                                       \
      const bool up = il1u ? ((T) < TT) : ((T) >= 1);                           \
      if (up) {                                                                 \
        float ig = sigm(acc[0]), fg = sigm(acc[1]);                             \
        float gg = tanh_f(acc[2]), og = sigm(acc[3]);                           \
        cS1 = fg*cS1 + ig*gg;                                                   \
        nxt[lm*XS + d1] = (_Float16)(og * tanh_f(cS1));                         \
      }                                                                         \
    }                                                                           \
    if (w16) {                                                                  \
      f32x4 acc = (f32x4){sbC[0], sbC[1], sbC[2], sbC[3]};                      \
      acc = MF(W16[0], a1, acc);                                                \
      acc = MF(W16[1], a2, acc);                                                \
      acc = MF(W16[2], a3, acc);                                                \
      if (hasC && (T) >= 1) {                                                   \
        float ig = sigm(acc[0]), fg = sigm(acc[1]);                             \
        float gg = tanh_f(acc[2]), og = sigm(acc[3]);                           \
        cC = fg*cC + ig*gg;                                                     \
        nxt[lm*XS + 102] = (_Float16)(og * tanh_f(cC));                         \
      }                                                                         \
    }                                                                           \
    if (vx && (T) + 1 < TT) st2(nxt + lb0, XC0);                                \
    BARRIER();                                                                  \
  } while (0)

  int t = 0;
  for (;;) {
    STEP(t, xA0, xB0);
    if (++t > TT) break;
    STEP(t, xB0, xA0);
    if (++t > TT) break;
  }
#undef STEP

  // ---- FC on h2(255) (bufA[1], cols 88..102) ----
  if (tid < SB*NC) {
    int s = tid / NC, n = tid % NC;
    float acc = b_fc[n];
    #pragma unroll
    for (int u = 0; u < H2; ++u)
      acc += (float)bufA[1][s][88 + u] * w_fc[n*H2 + u];
    out[((size_t)blk*SB + s)*NC + n] = acc;
  }
}

extern "C" void kernel_launch(void* const* d_in, const int* in_sizes, int n_in,
                              void* d_out, int out_size, void* d_ws, size_t ws_size,
                              hipStream_t stream) {
  (void)n_in; (void)d_ws; (void)ws_size; (void)out_size;
  const float* x     = (const float*)d_in[0];
  const float* w_ih1 = (const float*)d_in[1];
  const float* w_hh1 = (const float*)d_in[2];
  const float* b_ih1 = (const float*)d_in[3];
  const float* b_hh1 = (const float*)d_in[4];
  const float* w_ih2 = (const float*)d_in[5];
  const float* w_hh2 = (const float*)d_in[6];
  const float* b_ih2 = (const float*)d_in[7];
  const float* b_hh2 = (const float*)d_in[8];
  const float* w_fc  = (const float*)d_in[9];
  const float* b_fc  = (const float*)d_in[10];
  float* out = (float*)d_out;

  const int B = in_sizes[0] / (TT * I1);   // 4096
  dim3 grid(B / SB), block(NTH);
  lstm2_fused<<<grid, block, 0, stream>>>(x, w_ih1, w_hh1, b_ih1, b_hh1,
                                          w_ih2, w_hh2, b_ih2, b_hh2,
                                          w_fc, b_fc, out);
}